// Round 2
// baseline (174.799 us; speedup 1.0000x reference)
//
#include <hip/hip_runtime.h>
#include <cstdint>

#define KDIM 128
#define BATCH 131072
#define DT 0.01f

#define LDH 136    // Hbf row stride (bf16 elems); 272 B/row keeps every row 16B-aligned
#define LDP 68     // mu/om plane row stride (bf16 elems); 136 B/row -> conflict-free reads
#define WREG 2208  // per-wave LDS region (ushorts) = 4416 B; block total 17664 B

typedef __attribute__((ext_vector_type(8))) short short8x;   // MFMA A/B frag (8 bf16)
typedef __attribute__((ext_vector_type(4))) float float4x;   // MFMA C/D frag

__device__ __forceinline__ unsigned short f2bf(float f) {
    // round-to-nearest-even fp32 -> bf16 (finite inputs)
    unsigned int u = __float_as_uint(f);
    u += 0x7FFFu + ((u >> 16) & 1u);
    return (unsigned short)(u >> 16);
}
__device__ __forceinline__ float bf2f(unsigned short h) {
    return __uint_as_float((unsigned int)h << 16);
}
__device__ __forceinline__ float tanh_fast(float v) {
    float ax = fabsf(v);
    float e  = __expf(-2.0f * ax);
    float r  = __fdividef(1.0f - e, 1.0f + e);
    return copysignf(r, v);
}

// W[k][n] fp32 -> Wt[n][k] bf16, once per launch (MFMA B-frags want contiguous K)
__global__ void prep_weights(const float* __restrict__ W1, const float* __restrict__ W2,
                             unsigned short* __restrict__ W1t, unsigned short* __restrict__ W2t) {
    int idx = blockIdx.x * 256 + threadIdx.x;
    int n = idx & 127, k = idx >> 7;
    W1t[n * 128 + k] = f2bf(W1[idx]);
    W2t[n * 128 + k] = f2bf(W2[idx]);
}

// Fully wave-private, barrier-free: each wave owns 16 batch rows end-to-end.
__global__ __launch_bounds__(256) void koopman_main(
        const float* __restrict__ x, const float* __restrict__ b1,
        const float* __restrict__ b2, const unsigned short* __restrict__ W1t,
        const unsigned short* __restrict__ W2t, float* __restrict__ y) {
    __shared__ __align__(16) unsigned short smem[4 * WREG];

    const int tid  = threadIdx.x;
    const int lane = tid & 63;
    const int wave = tid >> 6;
    const int l15  = lane & 15;
    const int quad = lane >> 4;
    const int row0 = blockIdx.x * 64 + wave * 16;   // wave's 16 rows

    unsigned short* wbase = smem + wave * WREG;
    unsigned short* Hbf = wbase;                    // [16][LDH]  (phase A)
    unsigned short* Pmu = wbase;                    // [16][LDP]  (phase B, aliases Hbf)
    unsigned short* Pom = wbase + 16 * LDP + 8;     // [16][LDP]

    // ---- matmul-1 A-frags straight from global fp32 (no LDS, no barrier) ----
    // lane (l15,quad) needs x[row0+l15][ks*32 + quad*8 .. +7] for ks=0..3
    const float* xrow = x + (size_t)(row0 + l15) * KDIM + quad * 8;
    float4 xv[8];
    #pragma unroll
    for (int ks = 0; ks < 4; ++ks) {
        xv[2 * ks]     = *(const float4*)(xrow + ks * 32);
        xv[2 * ks + 1] = *(const float4*)(xrow + ks * 32 + 4);
    }
    short8x af[4];
    #pragma unroll
    for (int ks = 0; ks < 4; ++ks) {
        short8x t;
        t[0] = (short)f2bf(xv[2 * ks].x);
        t[1] = (short)f2bf(xv[2 * ks].y);
        t[2] = (short)f2bf(xv[2 * ks].z);
        t[3] = (short)f2bf(xv[2 * ks].w);
        t[4] = (short)f2bf(xv[2 * ks + 1].x);
        t[5] = (short)f2bf(xv[2 * ks + 1].y);
        t[6] = (short)f2bf(xv[2 * ks + 1].z);
        t[7] = (short)f2bf(xv[2 * ks + 1].w);
        af[ks] = t;
    }

    // ---- matmul 1: H1 = x @ W1 ----
    float4x acc[8];
    #pragma unroll
    for (int nt = 0; nt < 8; ++nt) acc[nt] = (float4x){0.f, 0.f, 0.f, 0.f};
    #pragma unroll
    for (int ks = 0; ks < 4; ++ks) {
        #pragma unroll
        for (int nt = 0; nt < 8; ++nt) {
            short8x bfr = *(const short8x*)&W1t[(nt * 16 + l15) * 128 + ks * 32 + quad * 8];
            acc[nt] = __builtin_amdgcn_mfma_f32_16x16x32_bf16(af[ks], bfr, acc[nt], 0, 0, 0);
        }
    }

    // ---- bias + tanh -> Hbf (C/D layout scatter; wave-private, program order) ----
    #pragma unroll
    for (int nt = 0; nt < 8; ++nt) {
        int col = nt * 16 + l15;
        float bb = b1[col];
        #pragma unroll
        for (int r = 0; r < 4; ++r) {
            Hbf[(quad * 4 + r) * LDH + col] = f2bf(tanh_fast(acc[nt][r] + bb));
        }
    }

    // ---- matmul 2: H2 = H1 @ W2 (A-frags gathered from wave-private Hbf) ----
    float4x acc2[8];
    #pragma unroll
    for (int nt = 0; nt < 8; ++nt) acc2[nt] = (float4x){0.f, 0.f, 0.f, 0.f};
    #pragma unroll
    for (int ks = 0; ks < 4; ++ks) {
        short8x a2 = *(const short8x*)&Hbf[l15 * LDH + ks * 32 + quad * 8];
        #pragma unroll
        for (int nt = 0; nt < 8; ++nt) {
            short8x bfr = *(const short8x*)&W2t[(nt * 16 + l15) * 128 + ks * 32 + quad * 8];
            acc2[nt] = __builtin_amdgcn_mfma_f32_16x16x32_bf16(a2, bfr, acc2[nt], 0, 0, 0);
        }
    }

    // ---- +b2 -> bf16 mu/om planes (dmu~4e-3 -> dy~2e-4, negligible) ----
    #pragma unroll
    for (int nt = 0; nt < 8; ++nt) {
        int col = nt * 16 + l15;
        float bb = b2[col];
        unsigned short* P = (col & 1) ? Pom : Pmu;
        int j = col >> 1;
        #pragma unroll
        for (int r = 0; r < 4; ++r) {
            P[(quad * 4 + r) * LDP + j] = f2bf(acc2[nt][r] + bb);
        }
    }

    // ---- epilogue: 2x2 rotation-scaling on fp32 x (coalesced float2, L1-warm) ----
    const float2* xg2 = (const float2*)(x + (size_t)row0 * KDIM);
    float2*       yg2 = (float2*)(y + (size_t)row0 * KDIM);
    #pragma unroll
    for (int i = 0; i < 16; ++i) {
        float mu = bf2f(Pmu[i * LDP + lane]);
        float om = bf2f(Pom[i * LDP + lane]);
        float2 xvp = xg2[i * 64 + lane];
        float ex = __expf(DT * mu);
        float s, c;
        __sincosf(DT * om, &s, &c);
        float2 yv;
        yv.x = ex * (c * xvp.x - s * xvp.y);
        yv.y = ex * (s * xvp.x + c * xvp.y);
        yg2[i * 64 + lane] = yv;
    }
}

extern "C" void kernel_launch(void* const* d_in, const int* in_sizes, int n_in,
                              void* d_out, int out_size, void* d_ws, size_t ws_size,
                              hipStream_t stream) {
    const float* x  = (const float*)d_in[0];
    const float* W1 = (const float*)d_in[1];
    const float* b1 = (const float*)d_in[2];
    const float* W2 = (const float*)d_in[3];
    const float* b2 = (const float*)d_in[4];
    float* y = (float*)d_out;

    unsigned short* W1t = (unsigned short*)d_ws;
    unsigned short* W2t = W1t + 128 * 128;

    prep_weights<<<64, 256, 0, stream>>>(W1, W2, W1t, W2t);
    koopman_main<<<BATCH / 64, 256, 0, stream>>>(x, b1, b2, W1t, W2t, y);
}

// Round 3
// 158.025 us; speedup vs baseline: 1.1061x; 1.1061x over previous
//
#include <hip/hip_runtime.h>
#include <cstdint>

#define KDIM 128
#define BATCH 131072
#define LDH 136    // bf16 LDS row stride: 272 B/row keeps 16B alignment, spreads banks

typedef __attribute__((ext_vector_type(8))) short short8x;          // MFMA A/B frag
typedef __attribute__((ext_vector_type(4))) float float4x;          // MFMA C/D frag
typedef __attribute__((ext_vector_type(4))) unsigned int uint4x;

// pack two fp32 -> bf16x2 dword, round-half-up (1 add per elem + 1 v_perm)
__device__ __forceinline__ unsigned int pk_bf16(float a, float b) {
    unsigned int ua = __float_as_uint(a) + 0x8000u;
    unsigned int ub = __float_as_uint(b) + 0x8000u;
    return __builtin_amdgcn_perm(ub, ua, 0x07060302u);  // {hi16(b), hi16(a)}
}

__device__ __forceinline__ unsigned short f2bf(float f) {   // RNE, prep kernel only
    unsigned int u = __float_as_uint(f);
    u += 0x7FFFu + ((u >> 16) & 1u);
    return (unsigned short)(u >> 16);
}

// clamped Pade tanh: err<=0.025 abs; y-sensitivity 0.05 -> <1.3e-3 in y. No transcendental.
__device__ __forceinline__ float tanh_pade(float v) {
    float z  = fminf(fmaxf(v, -4.0f), 4.0f);
    float z2 = z * z;
    float num = z * (27.0f + z2);
    float den = fmaf(z2, 9.0f, 27.0f);
    return num * __frcp_rn(den);
}

// W[k][n] fp32 -> Wt[n][k] bf16 (MFMA frags want contiguous K)
__global__ void prep_weights(const float* __restrict__ W1, const float* __restrict__ W2,
                             unsigned short* __restrict__ W1t, unsigned short* __restrict__ W2t) {
    int idx = blockIdx.x * 256 + threadIdx.x;
    int n = idx & 127, k = idx >> 7;
    W1t[n * 128 + k] = f2bf(W1[idx]);
    W2t[n * 128 + k] = f2bf(W2[idx]);
}

// Wave-private, barrier-free. M=32 rows/wave; operands swapped (A=W^T, B=X^T) so the
// MFMA output is row-in-lane: lane l15 holds rows {l15, l15+16}, 4 consecutive cols/frag.
__global__ __launch_bounds__(256, 4) void koopman_main(
        const float* __restrict__ x, const float* __restrict__ b1,
        const float* __restrict__ b2, const unsigned short* __restrict__ W1t,
        const unsigned short* __restrict__ W2t, float* __restrict__ y) {
    __shared__ __align__(16) unsigned short Hall[4 * 32 * LDH];   // 34816 B

    const int tid  = threadIdx.x;
    const int lane = tid & 63;
    const int wave = tid >> 6;
    const int l15  = lane & 15;
    const int quad = lane >> 4;
    const int row0 = blockIdx.x * 128 + wave * 32;

    unsigned short* Hbf = Hall + wave * (32 * LDH);

    // ---- load x frags: 16 float4 (HBM), pack to bf16 B-frags (X^T layout == A-layout data) ----
    short8x xf[2][4];
    #pragma unroll
    for (int h = 0; h < 2; ++h) {
        const float* xrow = x + (size_t)(row0 + 16 * h + l15) * KDIM + quad * 8;
        #pragma unroll
        for (int ks = 0; ks < 4; ++ks) {
            float4 v0 = *(const float4*)(xrow + ks * 32);
            float4 v1 = *(const float4*)(xrow + ks * 32 + 4);
            uint4x u;
            u[0] = pk_bf16(v0.x, v0.y);
            u[1] = pk_bf16(v0.z, v0.w);
            u[2] = pk_bf16(v1.x, v1.y);
            u[3] = pk_bf16(v1.z, v1.w);
            xf[h][ks] = __builtin_bit_cast(short8x, u);
        }
    }

    // ---- matmul 1: D[col][row] = W1^T @ X^T ; each W-frag feeds 2 MFMAs ----
    float4x acc[2][8];
    #pragma unroll
    for (int h = 0; h < 2; ++h)
        #pragma unroll
        for (int nt = 0; nt < 8; ++nt) acc[h][nt] = (float4x){0.f, 0.f, 0.f, 0.f};
    #pragma unroll
    for (int ks = 0; ks < 4; ++ks) {
        #pragma unroll
        for (int nt = 0; nt < 8; ++nt) {
            short8x w = *(const short8x*)&W1t[(nt * 16 + l15) * 128 + ks * 32 + quad * 8];
            acc[0][nt] = __builtin_amdgcn_mfma_f32_16x16x32_bf16(w, xf[0][ks], acc[0][nt], 0, 0, 0);
            acc[1][nt] = __builtin_amdgcn_mfma_f32_16x16x32_bf16(w, xf[1][ks], acc[1][nt], 0, 0, 0);
        }
    }

    // ---- bias + tanh -> packed b64 LDS writes (lane owns row l15+16h, cols nt*16+quad*4..+3) ----
    #pragma unroll
    for (int nt = 0; nt < 8; ++nt) {
        float4 bb = *(const float4*)&b1[nt * 16 + quad * 4];
        #pragma unroll
        for (int h = 0; h < 2; ++h) {
            float4x v = acc[h][nt];
            float t0 = tanh_pade(v[0] + bb.x);
            float t1 = tanh_pade(v[1] + bb.y);
            float t2 = tanh_pade(v[2] + bb.z);
            float t3 = tanh_pade(v[3] + bb.w);
            uint2 d;
            d.x = pk_bf16(t0, t1);
            d.y = pk_bf16(t2, t3);
            *(uint2*)&Hbf[(16 * h + l15) * LDH + nt * 16 + quad * 4] = d;
        }
    }

    // ---- matmul 2: D[col][row] = W2^T @ H^T (H B-frags: b128 reads, wave-private) ----
    float4x acc2[2][8];
    #pragma unroll
    for (int h = 0; h < 2; ++h)
        #pragma unroll
        for (int nt = 0; nt < 8; ++nt) acc2[h][nt] = (float4x){0.f, 0.f, 0.f, 0.f};
    #pragma unroll
    for (int ks = 0; ks < 4; ++ks) {
        short8x hf0 = *(const short8x*)&Hbf[l15 * LDH + ks * 32 + quad * 8];
        short8x hf1 = *(const short8x*)&Hbf[(16 + l15) * LDH + ks * 32 + quad * 8];
        #pragma unroll
        for (int nt = 0; nt < 8; ++nt) {
            short8x w = *(const short8x*)&W2t[(nt * 16 + l15) * 128 + ks * 32 + quad * 8];
            acc2[0][nt] = __builtin_amdgcn_mfma_f32_16x16x32_bf16(w, hf0, acc2[0][nt], 0, 0, 0);
            acc2[1][nt] = __builtin_amdgcn_mfma_f32_16x16x32_bf16(w, hf1, acc2[1][nt], 0, 0, 0);
        }
    }

    // ---- fused epilogue: mu/om pairs are in-lane; polynomial exp/sin/cos (|t|<=0.12) ----
    #pragma unroll
    for (int nt = 0; nt < 8; ++nt) {
        float4 bv = *(const float4*)&b2[nt * 16 + quad * 4];
        #pragma unroll
        for (int h = 0; h < 2; ++h) {
            size_t rowoff = (size_t)(row0 + 16 * h + l15) * KDIM + nt * 16 + quad * 4;
            float4 xv = *(const float4*)&x[rowoff];
            float4x v = acc2[h][nt];
            float4 out;
            {
                float tm = 0.01f * (v[0] + bv.x);
                float tw = 0.01f * (v[1] + bv.y);
                float tm2 = tm * tm, tw2 = tw * tw;
                float ex = fmaf(tm2, fmaf(tm, 0.16666667f, 0.5f), 1.0f + tm);
                float s  = tw * fmaf(tw2, -0.16666667f, 1.0f);
                float c  = fmaf(tw2, -0.5f, 1.0f);
                out.x = ex * fmaf(c, xv.x, -s * xv.y);
                out.y = ex * fmaf(s, xv.x,  c * xv.y);
            }
            {
                float tm = 0.01f * (v[2] + bv.z);
                float tw = 0.01f * (v[3] + bv.w);
                float tm2 = tm * tm, tw2 = tw * tw;
                float ex = fmaf(tm2, fmaf(tm, 0.16666667f, 0.5f), 1.0f + tm);
                float s  = tw * fmaf(tw2, -0.16666667f, 1.0f);
                float c  = fmaf(tw2, -0.5f, 1.0f);
                out.z = ex * fmaf(c, xv.z, -s * xv.w);
                out.w = ex * fmaf(s, xv.z,  c * xv.w);
            }
            *(float4*)&y[rowoff] = out;
        }
    }
}

extern "C" void kernel_launch(void* const* d_in, const int* in_sizes, int n_in,
                              void* d_out, int out_size, void* d_ws, size_t ws_size,
                              hipStream_t stream) {
    const float* x  = (const float*)d_in[0];
    const float* W1 = (const float*)d_in[1];
    const float* b1 = (const float*)d_in[2];
    const float* W2 = (const float*)d_in[3];
    const float* b2 = (const float*)d_in[4];
    float* y = (float*)d_out;

    unsigned short* W1t = (unsigned short*)d_ws;
    unsigned short* W2t = W1t + 128 * 128;

    prep_weights<<<64, 256, 0, stream>>>(W1, W2, W1t, W2t);
    koopman_main<<<BATCH / 128, 256, 0, stream>>>(x, b1, b2, W1t, W2t, y);
}